// Round 9
// baseline (449.090 us; speedup 1.0000x reference)
//
#include <hip/hip_runtime.h>
#include <hip/hip_bf16.h>
#include <cstdint>

#define AS1 __attribute__((address_space(1)))
#define AS3 __attribute__((address_space(3)))

typedef __bf16 bf16x8 __attribute__((ext_vector_type(8)));
typedef float  f32x16 __attribute__((ext_vector_type(16)));

__device__ __forceinline__ void gld_lds16(const void* g, void* l) {
    __builtin_amdgcn_global_load_lds((const AS1 void*)g, (AS3 void*)l, 16, 0, 0);
}

// ---------------- Kernel 0: rotated 3x3 kernels (exact fp32 replica), ONCE ----------------
__global__ void k_rot(const float* __restrict__ base, float* __restrict__ w1) {
    int m = threadIdx.x;            // 0..127 = g*16+o
    int g = m >> 4, o = m & 15;
    float th = 6.28318530717958647692f * (float)g / 8.0f;
    float c = cosf(th), s = sinf(th);
    for (int i = 0; i < 3; ++i) {
        float ys = (2.0f * i + 1.0f) / 3.0f - 1.0f;
        for (int j = 0; j < 3; ++j) {
            float xs = (2.0f * j + 1.0f) / 3.0f - 1.0f;
            float gx = c * xs - s * ys;
            float gy = s * xs + c * ys;
            float px = ((gx + 1.0f) * 3.0f - 1.0f) * 0.5f;
            float py = ((gy + 1.0f) * 3.0f - 1.0f) * 0.5f;
            float x0 = floorf(px), y0 = floorf(py);
            float wx = px - x0, wy = py - y0;
            int x0i = (int)x0, y0i = (int)y0;
            auto gat = [&](int yi, int xi) -> float {
                bool v = (yi >= 0) && (yi < 3) && (xi >= 0) && (xi < 3);
                int yc = min(max(yi, 0), 2), xc = min(max(xi, 0), 2);
                return v ? base[o * 9 + yc * 3 + xc] : 0.0f;
            };
            w1[m * 9 + i * 3 + j] =
                  gat(y0i, x0i)         * (1.0f - wx) * (1.0f - wy)
                + gat(y0i, x0i + 1)     * wx          * (1.0f - wy)
                + gat(y0i + 1, x0i)     * (1.0f - wx) * wy
                + gat(y0i + 1, x0i + 1) * wx          * wy;
        }
    }
}

// ---------------- Kernel 1: conv1 + relu -> channel-last padded bf16 h ----------------
// hl layout: [b][yy 0..29][xx 0..29][c 0..127], borders = 0.
// A is written in MFMA-FRAGMENT-LINEAR order:
//   A_byte = (t*2+mh)*16384 + (i2*4+ks)*1024 + lane*16  (1KB per fragment block)
// => an MFMA A-fragment is ONE fully-coalesced 1KB global load.
__global__ __launch_bounds__(256) void k_conv1(const float* __restrict__ x,
                                               const float* __restrict__ w1g,
                                               const float* __restrict__ w2,
                                               __hip_bfloat16* __restrict__ hl,
                                               __hip_bfloat16* __restrict__ A) {
    int tid = threadIdx.x;

    if (blockIdx.x < 1152) {
        int i = blockIdx.x * 256 + tid;
        int r = i / 1152, k = i - r * 1152;
        int g = r >> 5, o2 = r & 31;
        int kk = k >> 7, cch = k & 127;
        int ky = kk / 3, kx = kk - ky * 3;
        int c2 = cch >> 3, hh = cch & 7;
        int gi = (g - hh) & 7;
        float val = w2[((o2 * 16 + c2) * 8 + gi) * 9 + ky * 3 + kx];
        // fragment-linear placement
        int half = cch >> 6, kt = cch & 63;
        int t = kk * 2 + half, ks2 = kt >> 4, hi2 = (kt >> 3) & 1, e = kt & 7;
        int mh = r >> 7, i2 = (r >> 5) & 3, row = r & 31;
        int aidx = ((((t * 2 + mh) * 16) + i2 * 4 + ks2) << 9) + ((hi2 << 5) + row) * 8 + e;
        A[aidx] = __float2bfloat16(val);
    }

    __shared__ float w1s[1152];
    for (int i = tid; i < 1152; i += 256) w1s[i] = w1g[i];
    __syncthreads();

    const int c0 = (tid & 15) * 8;
    float wreg[8][9];
#pragma unroll
    for (int cc = 0; cc < 8; ++cc)
#pragma unroll
        for (int k = 0; k < 9; ++k) wreg[cc][k] = w1s[(c0 + cc) * 9 + k];

    const int slot = tid >> 4;                    // 0..15
    const int band = blockIdx.x % 15;
    const int b    = blockIdx.x / 15;
    const int yy   = band * 2 + (slot >> 3);      // padded row 0..29
    const int xx0  = (slot & 7) * 4;              // 0,4,...,28

    const float* xb = x + b * 784;
    float xv[3][6];
#pragma unroll
    for (int t = 0; t < 3; ++t) {
        int sy = yy - 2 + t;
        bool syok = (sy >= 0) && (sy < 28);
#pragma unroll
        for (int u = 0; u < 6; ++u) {
            int sx = xx0 - 2 + u;
            bool ok = syok && (sx >= 0) && (sx < 28);
            xv[t][u] = ok ? xb[sy * 28 + sx] : 0.0f;
        }
    }

    float acc[4][8];
#pragma unroll
    for (int j = 0; j < 4; ++j)
#pragma unroll
        for (int cc = 0; cc < 8; ++cc) acc[j][cc] = 0.0f;

#pragma unroll
    for (int t = 0; t < 3; ++t)
#pragma unroll
        for (int u = 0; u < 3; ++u) {
#pragma unroll
            for (int j = 0; j < 4; ++j) {
                float xvv = xv[t][j + u];
#pragma unroll
                for (int cc = 0; cc < 8; ++cc)
                    acc[j][cc] += xvv * wreg[cc][t * 3 + u];
            }
        }

#pragma unroll
    for (int j = 0; j < 4; ++j) {
        int xx = xx0 + j;
        if (xx < 30) {
            bool interior = (yy >= 1) && (yy <= 28) && (xx >= 1) && (xx <= 28);
            union { __hip_bfloat16 h[8]; float4 f4; } u;
#pragma unroll
            for (int cc = 0; cc < 8; ++cc)
                u.h[cc] = __float2bfloat16(interior ? fmaxf(acc[j][cc], 0.0f) : 0.0f);
            int pi = b * 900 + yy * 30 + xx;
            *(float4*)(hl + (size_t)pi * 128 + c0) = u.f4;
        }
    }
}

// ---------------- Kernel 2: conv2 implicit GEMM — BARRIER-FREE, robust vmcnt ----
// Block = 128(M half, mh) x 512(N), 8 waves side-by-side in N (wave tile 128x64).
// Each wave's B slice (64 N x 64 K = 8KB) is DISJOINT -> wave-private 2x8KB LDS
// double buffer; ZERO __syncthreads. A is global->reg from frag-linear A (1KB
// coalesced loads; all 8 waves read the same 16KB/tile -> L1-hot).
// Wait discipline (R8 post-mortem: SGB can't order same-class VMEM; this scheme is
// order-robust): per iter: {16 aF global} -> s_waitcnt vmcnt(16) -> {8 bF ds_read}
// -> {8 stage gld_lds} -> {32 MFMA}. The asm's memory clobber pins stage(t) [prev
// iter] BEFORE aF(t), so in-order vmcnt(16) drains exactly stage(t). ks3's
// compiler-inserted wait for aF[3] (older than stage(t+1)) forces vmcnt<=8 at iter
// end -> induction holds. Waves drift freely; stalls covered by SIMD sibling.
__global__ __launch_bounds__(512, 2) void k_conv2(const __hip_bfloat16* __restrict__ A,
                                                  const __hip_bfloat16* __restrict__ hl,
                                                  __hip_bfloat16* __restrict__ p) {
    __shared__ __align__(16) char smem[131072];   // 8 waves x (2 x 8KB)

    const int tid  = threadIdx.x;
    const int lane = tid & 63;
    const int w    = tid >> 6;          // 0..7 = wave's N-slot
    const int hi   = lane >> 5;

    const int bid = blockIdx.x;         // grid 1568 = 784 nchunks x 2 mh
    const int mh  = bid & 1;
    const int ncr = bid >> 1;
    const int nc  = (ncr & 7) * 98 + (ncr >> 3);   // bijective XCD swizzle (784=8*98)
    const int n0w = nc * 512 + w * 64;  // wave's N-base

    char* myLds = smem + w * 16384;

    // ---- B staging addresses: q=0..7 covers slice rows 8q..8q+7 ----
    // lane l -> row rl = 8q+(l>>3), slot l&7; pre-swizzled source col
    // ca = (l&7) ^ (rl&7) ^ (q&3)   [q&3 == (rl>>3)&3]
    uint32_t bSrc[8];
#pragma unroll
    for (int q = 0; q < 8; ++q) {
        int rl = q * 8 + (lane >> 3);
        int ca = (lane & 7) ^ (rl & 7) ^ (q & 3);
        int n = n0w + rl;
        int b = n / 784; int rr = n - b * 784;
        int y = rr / 28; int xx = rr - y * 28;
        bSrc[q] = (uint32_t)(((b * 30 + y) * 30 + xx) * 256 + ca * 16);
    }

    // ---- B fragment read addresses (slice-local), j=0..1 ----
    uint32_t bRd[2]; int bSw[2];
#pragma unroll
    for (int j = 0; j < 2; ++j) {
        int rl = j * 32 + (lane & 31);                 // 0..63
        bRd[j] = (uint32_t)(rl * 128);
        bSw[j] = (rl & 7) ^ ((rl >> 3) & 3);
    }

    // ---- A fragment GLOBAL base: + t*32768 + (i*4+ks)*1024 ----
    const char* gA = (const char*)A + mh * 16384 + lane * 16;
    const char* Hb = (const char*)hl;

    f32x16 acc[4][2];
#pragma unroll
    for (int i = 0; i < 4; ++i)
#pragma unroll
        for (int j = 0; j < 2; ++j) acc[i][j] = (f32x16)(0.0f);

    auto stageB = [&](int tt, uint32_t dstOff) {
        int kk = tt >> 1, half = tt & 1;
        int ky = kk / 3, kx = kk - ky * 3;
        uint32_t boff = (uint32_t)((ky * 30 + kx) * 256 + half * 128);
#pragma unroll
        for (int q = 0; q < 8; ++q)
            gld_lds16(Hb + bSrc[q] + boff, myLds + dstOff + q * 1024);
    };

    // ---- prologue: stage tile 0 into buf0 (8 gld_lds outstanding) ----
    stageB(0, 0);

#pragma unroll 1
    for (int t = 0; t < 18; ++t) {
        const uint32_t cur = (uint32_t)((t & 1) << 13);
        const uint32_t nxt = cur ^ 8192u;
        const char* gAt = gA + (size_t)t * 32768;

        // 1) 16 aF global loads for tile t (younger than stage(t) by construction)
        bf16x8 aF[4][4];
#pragma unroll
        for (int ks = 0; ks < 4; ++ks)
#pragma unroll
            for (int i = 0; i < 4; ++i)
                aF[ks][i] = *(const bf16x8*)(gAt + ((i * 4 + ks) << 10));

        // 2) drain exactly stage(t): outstanding = 8 stage + 16 aF -> vmcnt(16)
        asm volatile("s_waitcnt vmcnt(16)" ::: "memory");
        __builtin_amdgcn_sched_barrier(0);

        // 3) 8 bF ds_reads from buf[cur] (provably staged)
        bf16x8 bF[4][2];
#pragma unroll
        for (int ks = 0; ks < 4; ++ks)
#pragma unroll
            for (int j = 0; j < 2; ++j)
                bF[ks][j] = *(const bf16x8*)(myLds + cur + bRd[j] + ((uint32_t)((ks * 2 + hi) ^ bSw[j]) << 4));

        // 4) stage tile t+1 into buf[nxt] (youngest VMEM of this iter)
        if (t < 17) stageB(t + 1, nxt);

        // 5) 32 MFMAs (compiler auto-waits lgkm for bF, vmcnt for aF)
#pragma unroll
        for (int ks = 0; ks < 4; ++ks)
#pragma unroll
            for (int i = 0; i < 4; ++i)
#pragma unroll
                for (int j = 0; j < 2; ++j)
                    acc[i][j] = __builtin_amdgcn_mfma_f32_32x32x16_bf16(aF[ks][i], bF[ks][j], acc[i][j], 0, 0, 0);
    }

    // ---- epilogue: relu + mean over 8 consecutive M-rows; bf16 store ----
#pragma unroll
    for (int i = 0; i < 4; ++i) {
#pragma unroll
        for (int j = 0; j < 2; ++j) {
            f32x16 v = acc[i][j];
#pragma unroll
            for (int u = 0; u < 4; ++u) {
                float sv = fmaxf(v[4*u], 0.0f) + fmaxf(v[4*u+1], 0.0f)
                         + fmaxf(v[4*u+2], 0.0f) + fmaxf(v[4*u+3], 0.0f);
                sv += __shfl_xor(sv, 32, 64);
                if (hi == 0) {
                    int a = mh * 16 + i * 4 + u;
                    int n = nc * 512 + w * 64 + j * 32 + (lane & 31);
                    int b = n / 784; int rr = n - b * 784;
                    p[(b * 32 + a) * 784 + rr] = __float2bfloat16(sv * 0.125f);
                }
            }
        }
    }
}

// ---------------- Kernel 3: FC — 4-way k-split, bf16 p reads ----------------
__global__ __launch_bounds__(256) void k_fc(const __hip_bfloat16* __restrict__ p,
                                            const float* __restrict__ fw,
                                            const float* __restrict__ fb,
                                            float* __restrict__ out) {
    int b = blockIdx.x >> 2, ks = blockIdx.x & 3;
    int tid = threadIdx.x;
    const bf16x8* pb = (const bf16x8*)(p + (size_t)b * 25088);
    const float4* w4 = (const float4*)fw;
    float acc[10] = {};
    for (int t = ks * 784 + tid; t < (ks + 1) * 784; t += 256) {
        union { bf16x8 v; __hip_bfloat16 h[8]; } u;
        u.v = pb[t];
        float vf[8];
#pragma unroll
        for (int e = 0; e < 8; ++e) vf[e] = __bfloat162float(u.h[e]);
#pragma unroll
        for (int c = 0; c < 10; ++c) {
            float4 u0 = w4[c * 6272 + 2 * t];
            float4 u1 = w4[c * 6272 + 2 * t + 1];
            acc[c] += vf[0] * u0.x + vf[1] * u0.y + vf[2] * u0.z + vf[3] * u0.w
                    + vf[4] * u1.x + vf[5] * u1.y + vf[6] * u1.z + vf[7] * u1.w;
        }
    }
    __shared__ float red[10][4];
    int lane = tid & 63, wv = tid >> 6;
#pragma unroll
    for (int c = 0; c < 10; ++c) {
        float s = acc[c];
#pragma unroll
        for (int o = 32; o > 0; o >>= 1) s += __shfl_down(s, o, 64);
        if (lane == 0) red[c][wv] = s;
    }
    __syncthreads();
    if (tid < 10) {
        float s = red[tid][0] + red[tid][1] + red[tid][2] + red[tid][3];
        if (ks == 0) s += fb[tid];
        atomicAdd(&out[b * 10 + tid], s);
    }
}

// ---------------- launch ----------------
extern "C" void kernel_launch(void* const* d_in, const int* in_sizes, int n_in,
                              void* d_out, int out_size, void* d_ws, size_t ws_size,
                              hipStream_t stream) {
    const float* x  = (const float*)d_in[0];
    const float* bw = (const float*)d_in[1];
    const float* w2 = (const float*)d_in[2];
    const float* fw = (const float*)d_in[3];
    const float* fb = (const float*)d_in[4];
    float* out = (float*)d_out;
    char* ws = (char*)d_ws;

    float*          w1   = (float*)(ws);
    __hip_bfloat16* Amat = (__hip_bfloat16*)(ws + 4608);
    __hip_bfloat16* hl   = (__hip_bfloat16*)(ws + 594432);
    __hip_bfloat16* p    = (__hip_bfloat16*)(ws + 118563328);

    hipMemsetAsync(d_out, 0, (size_t)out_size * sizeof(float), stream);
    k_rot  <<<1,    128, 0, stream>>>(bw, w1);
    k_conv1<<<7680, 256, 0, stream>>>(x, w1, w2, hl, Amat);
    k_conv2<<<1568, 512, 0, stream>>>(Amat, hl, p);
    k_fc   <<<2048, 256, 0, stream>>>(p, fw, fb, out);
}

// Round 10
// 345.636 us; speedup vs baseline: 1.2993x; 1.2993x over previous
//
#include <hip/hip_runtime.h>
#include <hip/hip_bf16.h>
#include <cstdint>

#define AS1 __attribute__((address_space(1)))
#define AS3 __attribute__((address_space(3)))

typedef __bf16 bf16x8 __attribute__((ext_vector_type(8)));
typedef float  f32x16 __attribute__((ext_vector_type(16)));

__device__ __forceinline__ void gld_lds16(const void* g, void* l) {
    __builtin_amdgcn_global_load_lds((const AS1 void*)g, (AS3 void*)l, 16, 0, 0);
}

// ---------------- Kernel 0: rotated 3x3 kernels + A-matrix build ----------------
// Block 0: w1 (exact fp32 replica of the bilinear rotation), threads 0..127.
// Blocks 1..1152: build the bf16 GEMM A matrix in MFMA-FRAGMENT-LINEAR order
// (moved out of k_conv1 so all conv1 blocks are uniform).
__global__ __launch_bounds__(256) void k_rot(const float* __restrict__ base,
                                             const float* __restrict__ w2,
                                             float* __restrict__ w1,
                                             __hip_bfloat16* __restrict__ A) {
    int tid = threadIdx.x;
    if (blockIdx.x == 0) {
        if (tid < 128) {
            int m = tid;                // 0..127 = g*16+o
            int g = m >> 4, o = m & 15;
            float th = 6.28318530717958647692f * (float)g / 8.0f;
            float c = cosf(th), s = sinf(th);
            for (int i = 0; i < 3; ++i) {
                float ys = (2.0f * i + 1.0f) / 3.0f - 1.0f;
                for (int j = 0; j < 3; ++j) {
                    float xs = (2.0f * j + 1.0f) / 3.0f - 1.0f;
                    float gx = c * xs - s * ys;
                    float gy = s * xs + c * ys;
                    float px = ((gx + 1.0f) * 3.0f - 1.0f) * 0.5f;
                    float py = ((gy + 1.0f) * 3.0f - 1.0f) * 0.5f;
                    float x0 = floorf(px), y0 = floorf(py);
                    float wx = px - x0, wy = py - y0;
                    int x0i = (int)x0, y0i = (int)y0;
                    auto gat = [&](int yi, int xi) -> float {
                        bool v = (yi >= 0) && (yi < 3) && (xi >= 0) && (xi < 3);
                        int yc = min(max(yi, 0), 2), xc = min(max(xi, 0), 2);
                        return v ? base[o * 9 + yc * 3 + xc] : 0.0f;
                    };
                    w1[m * 9 + i * 3 + j] =
                          gat(y0i, x0i)         * (1.0f - wx) * (1.0f - wy)
                        + gat(y0i, x0i + 1)     * wx          * (1.0f - wy)
                        + gat(y0i + 1, x0i)     * (1.0f - wx) * wy
                        + gat(y0i + 1, x0i + 1) * wx          * wy;
                }
            }
        }
    } else {
        int i = (blockIdx.x - 1) * 256 + tid;
        int r = i / 1152, k = i - r * 1152;
        int g = r >> 5, o2 = r & 31;
        int kk = k >> 7, cch = k & 127;
        int ky = kk / 3, kx = kk - ky * 3;
        int c2 = cch >> 3, hh = cch & 7;
        int gi = (g - hh) & 7;
        float val = w2[((o2 * 16 + c2) * 8 + gi) * 9 + ky * 3 + kx];
        // fragment-linear placement:
        //   A_byte = (t*2+mh)*16384 + (i2*4+ks)*1024 + (hi*32+row)*16 + e*2
        int half = cch >> 6, kt = cch & 63;
        int t = kk * 2 + half, ks2 = kt >> 4, hi2 = (kt >> 3) & 1, e = kt & 7;
        int mh = r >> 7, i2 = (r >> 5) & 3, row = r & 31;
        int aidx = ((((t * 2 + mh) * 16) + i2 * 4 + ks2) << 9) + ((hi2 << 5) + row) * 8 + e;
        A[aidx] = __float2bfloat16(val);
    }
}

// ---------------- Kernel 1: conv1 + relu -> channel-last padded bf16 h ----------------
// hl layout: [b][yy 0..29][xx 0..29][c 0..127], borders = 0. Uniform blocks (A-build
// moved to k_rot).
__global__ __launch_bounds__(256) void k_conv1(const float* __restrict__ x,
                                               const float* __restrict__ w1g,
                                               __hip_bfloat16* __restrict__ hl) {
    int tid = threadIdx.x;

    __shared__ float w1s[1152];
    for (int i = tid; i < 1152; i += 256) w1s[i] = w1g[i];
    __syncthreads();

    const int c0 = (tid & 15) * 8;
    float wreg[8][9];
#pragma unroll
    for (int cc = 0; cc < 8; ++cc)
#pragma unroll
        for (int k = 0; k < 9; ++k) wreg[cc][k] = w1s[(c0 + cc) * 9 + k];

    const int slot = tid >> 4;                    // 0..15
    const int band = blockIdx.x % 15;
    const int b    = blockIdx.x / 15;
    const int yy   = band * 2 + (slot >> 3);      // padded row 0..29
    const int xx0  = (slot & 7) * 4;              // 0,4,...,28

    const float* xb = x + b * 784;
    float xv[3][6];
#pragma unroll
    for (int t = 0; t < 3; ++t) {
        int sy = yy - 2 + t;
        bool syok = (sy >= 0) && (sy < 28);
#pragma unroll
        for (int u = 0; u < 6; ++u) {
            int sx = xx0 - 2 + u;
            bool ok = syok && (sx >= 0) && (sx < 28);
            xv[t][u] = ok ? xb[sy * 28 + sx] : 0.0f;
        }
    }

    float acc[4][8];
#pragma unroll
    for (int j = 0; j < 4; ++j)
#pragma unroll
        for (int cc = 0; cc < 8; ++cc) acc[j][cc] = 0.0f;

#pragma unroll
    for (int t = 0; t < 3; ++t)
#pragma unroll
        for (int u = 0; u < 3; ++u) {
#pragma unroll
            for (int j = 0; j < 4; ++j) {
                float xvv = xv[t][j + u];
#pragma unroll
                for (int cc = 0; cc < 8; ++cc)
                    acc[j][cc] += xvv * wreg[cc][t * 3 + u];
            }
        }

#pragma unroll
    for (int j = 0; j < 4; ++j) {
        int xx = xx0 + j;
        if (xx < 30) {
            bool interior = (yy >= 1) && (yy <= 28) && (xx >= 1) && (xx <= 28);
            union { __hip_bfloat16 h[8]; float4 f4; } u;
#pragma unroll
            for (int cc = 0; cc < 8; ++cc)
                u.h[cc] = __float2bfloat16(interior ? fmaxf(acc[j][cc], 0.0f) : 0.0f);
            int pi = b * 900 + yy * 30 + xx;
            *(float4*)(hl + (size_t)pi * 128 + c0) = u.f4;
        }
    }
}

// ---------------- Kernel 2: conv2 implicit GEMM — R4 (verified best: 234 µs) ----
// frag-linear A (32KB linear staging, lane-linear conflict-free reads) + XOR-swizzled
// B (pre-swizzled gld_lds source); 8 waves x 128x64; one __syncthreads per K-tile;
// SGB program pinning {staging, ks0-frags, 1:1 MFMA:ds_read interleave}.
__global__ __launch_bounds__(512, 2) void k_conv2(const __hip_bfloat16* __restrict__ A,
                                                  const __hip_bfloat16* __restrict__ hl,
                                                  __hip_bfloat16* __restrict__ p) {
    __shared__ __align__(16) char smem[131072];   // 2 x (A 32KB | B 32KB)

    const int tid  = threadIdx.x;
    const int lane = tid & 63;
    const int w    = tid >> 6;          // 0..7
    const int hi   = lane >> 5;
    const int wqr  = w >> 2;            // 0..1  M-group (128 rows each)
    const int wqc  = w & 3;             // 0..3  N-group (64 cols each)

    const int bid = blockIdx.x;         // grid 1568 = 8 * 196
    const int nt  = (bid & 7) * 196 + (bid >> 3);   // bijective XCD swizzle
    const int n0  = nt << 8;            // 256 N per tile

    // ---- B staging addresses: wave w stages ch = 2w+q of each 16KB half ----
    uint32_t bSrc[2][2], ldsCh[2];
#pragma unroll
    for (int q = 0; q < 2; ++q) {
        int ch = 2 * w + q;
        int rl = ch * 8 + (lane >> 3);                 // row within 128-row half
        int ca = (lane & 7) ^ (rl & 7) ^ (ch & 3);     // pre-swizzled 16B column
        ldsCh[q] = (uint32_t)(ch * 1024);
#pragma unroll
        for (int hn = 0; hn < 2; ++hn) {
            int n = n0 + hn * 128 + rl;
            int b = n / 784; int rr = n - b * 784;
            int y = rr / 28; int xx = rr - y * 28;
            bSrc[q][hn] = (uint32_t)(((b * 30 + y) * 30 + xx) * 256 + ca * 16);
        }
    }

    // ---- B fragment read addresses (2 frags per wave), relative to B base ----
    uint32_t bRd[2]; int bSw[2];
#pragma unroll
    for (int j = 0; j < 2; ++j) {
        int r = wqc * 64 + j * 32 + (lane & 31);       // 0..255
        bRd[j] = (uint32_t)((r >> 7) * 16384 + (r & 127) * 128);
        bSw[j] = (r & 7) ^ ((r >> 3) & 3);
    }

    // ---- A read base: wave's m-half block, lane-linear ----
    const uint32_t aRd = (uint32_t)(wqr * 16384 + lane * 16);

    f32x16 acc[4][2];
#pragma unroll
    for (int i = 0; i < 4; ++i)
#pragma unroll
        for (int j = 0; j < 2; ++j) acc[i][j] = (f32x16)(0.0f);

    const char* Ab = (const char*)A;
    const char* Hb = (const char*)hl;

    auto stage = [&](int tt, char* dst) {
        // A: contiguous 32KB at tt*32768, fully linear
#pragma unroll
        for (int q = 0; q < 4; ++q)
            gld_lds16(Ab + (size_t)tt * 32768 + q * 8192 + tid * 16,
                      dst + q * 8192 + tid * 16);
        // B: pre-swizzled source, linear dest
        int kk = tt >> 1, half = tt & 1;
        int ky = kk / 3, kx = kk - ky * 3;
        uint32_t boff = (uint32_t)((ky * 30 + kx) * 256 + half * 128);
        gld_lds16(Hb + bSrc[0][0] + boff, dst + 32768 + ldsCh[0]);
        gld_lds16(Hb + bSrc[1][0] + boff, dst + 32768 + ldsCh[1]);
        gld_lds16(Hb + bSrc[0][1] + boff, dst + 49152 + ldsCh[0]);
        gld_lds16(Hb + bSrc[1][1] + boff, dst + 49152 + ldsCh[1]);
    };

    // ---- prologue: stage tile 0 into buf0 ----
    stage(0, smem);

#pragma unroll 1
    for (int t = 0; t < 17; ++t) {
        __syncthreads();             // drains staging of tile t (issued last iter)
        char* cur = smem + ((t & 1) << 16);
        const char* LA = cur + aRd;
        const char* LB = cur + 32768;
        stage(t + 1, smem + (((t + 1) & 1) << 16));   // unconditional: body branch-free

        bf16x8 aF[2][4], bF[2][2];
        // ks0 fragments
#pragma unroll
        for (int i = 0; i < 4; ++i)
            aF[0][i] = *(const bf16x8*)(LA + ((i * 4 + 0) << 10));
#pragma unroll
        for (int j = 0; j < 2; ++j)
            bF[0][j] = *(const bf16x8*)(LB + bRd[j] + ((uint32_t)((0 + hi) ^ bSw[j]) << 4));

#pragma unroll
        for (int ks = 0; ks < 4; ++ks) {
            const int c = ks & 1, nx = c ^ 1;
            if (ks < 3) {
#pragma unroll
                for (int i = 0; i < 4; ++i)
                    aF[nx][i] = *(const bf16x8*)(LA + ((i * 4 + ks + 1) << 10));
#pragma unroll
                for (int j = 0; j < 2; ++j)
                    bF[nx][j] = *(const bf16x8*)(LB + bRd[j] + ((uint32_t)(((ks + 1) * 2 + hi) ^ bSw[j]) << 4));
            }
#pragma unroll
            for (int i = 0; i < 4; ++i)
#pragma unroll
                for (int j = 0; j < 2; ++j)
                    acc[i][j] = __builtin_amdgcn_mfma_f32_32x32x16_bf16(aF[c][i], bF[c][j], acc[i][j], 0, 0, 0);
        }

        // ---- scheduling program for this region ----
        // masks: MFMA=0x8, VMEM|VMEM_READ=0x30, DS_READ=0x100
        __builtin_amdgcn_sched_group_barrier(0x030, 8, 0);   // staging first
        __builtin_amdgcn_sched_group_barrier(0x100, 6, 0);   // ks0 frags
#pragma unroll
        for (int ks = 0; ks < 3; ++ks) {
#pragma unroll
            for (int r = 0; r < 6; ++r) {
                __builtin_amdgcn_sched_group_barrier(0x008, 1, 0);
                __builtin_amdgcn_sched_group_barrier(0x100, 1, 0);
            }
            __builtin_amdgcn_sched_group_barrier(0x008, 2, 0);
        }
        __builtin_amdgcn_sched_group_barrier(0x008, 8, 0);   // ks3 MFMAs
    }

    // ---- drain: tile 17 from buf1, no staging ----
    {
        __syncthreads();
        char* cur = smem + 65536;
        const char* LA = cur + aRd;
        const char* LB = cur + 32768;

        bf16x8 aF[2][4], bF[2][2];
#pragma unroll
        for (int i = 0; i < 4; ++i)
            aF[0][i] = *(const bf16x8*)(LA + ((i * 4 + 0) << 10));
#pragma unroll
        for (int j = 0; j < 2; ++j)
            bF[0][j] = *(const bf16x8*)(LB + bRd[j] + ((uint32_t)((0 + hi) ^ bSw[j]) << 4));

#pragma unroll
        for (int ks = 0; ks < 4; ++ks) {
            const int c = ks & 1, nx = c ^ 1;
            if (ks < 3) {
#pragma unroll
                for (int i = 0; i < 4; ++i)
                    aF[nx][i] = *(const bf16x8*)(LA + ((i * 4 + ks + 1) << 10));
#pragma unroll
                for (int j = 0; j < 2; ++j)
                    bF[nx][j] = *(const bf16x8*)(LB + bRd[j] + ((uint32_t)(((ks + 1) * 2 + hi) ^ bSw[j]) << 4));
            }
#pragma unroll
            for (int i = 0; i < 4; ++i)
#pragma unroll
                for (int j = 0; j < 2; ++j)
                    acc[i][j] = __builtin_amdgcn_mfma_f32_32x32x16_bf16(aF[c][i], bF[c][j], acc[i][j], 0, 0, 0);
        }
    }

    // ---- epilogue: relu + mean over 8 consecutive M-rows; bf16 store ----
#pragma unroll
    for (int i = 0; i < 4; ++i) {
#pragma unroll
        for (int j = 0; j < 2; ++j) {
            f32x16 v = acc[i][j];
#pragma unroll
            for (int u = 0; u < 4; ++u) {
                float sv = fmaxf(v[4*u], 0.0f) + fmaxf(v[4*u+1], 0.0f)
                         + fmaxf(v[4*u+2], 0.0f) + fmaxf(v[4*u+3], 0.0f);
                sv += __shfl_xor(sv, 32, 64);
                if (hi == 0) {
                    int a = wqr * 16 + i * 4 + u;
                    int n = n0 + wqc * 64 + j * 32 + (lane & 31);
                    int b = n / 784; int rr = n - b * 784;
                    p[(b * 32 + a) * 784 + rr] = __float2bfloat16(sv * 0.125f);
                }
            }
        }
    }
}

// ---------------- Kernel 3: FC — 4-way k-split, bf16 p reads ----------------
__global__ __launch_bounds__(256) void k_fc(const __hip_bfloat16* __restrict__ p,
                                            const float* __restrict__ fw,
                                            const float* __restrict__ fb,
                                            float* __restrict__ out) {
    int b = blockIdx.x >> 2, ks = blockIdx.x & 3;
    int tid = threadIdx.x;
    const bf16x8* pb = (const bf16x8*)(p + (size_t)b * 25088);
    const float4* w4 = (const float4*)fw;
    float acc[10] = {};
    for (int t = ks * 784 + tid; t < (ks + 1) * 784; t += 256) {
        union { bf16x8 v; __hip_bfloat16 h[8]; } u;
        u.v = pb[t];
        float vf[8];
#pragma unroll
        for (int e = 0; e < 8; ++e) vf[e] = __bfloat162float(u.h[e]);
#pragma unroll
        for (int c = 0; c < 10; ++c) {
            float4 u0 = w4[c * 6272 + 2 * t];
            float4 u1 = w4[c * 6272 + 2 * t + 1];
            acc[c] += vf[0] * u0.x + vf[1] * u0.y + vf[2] * u0.z + vf[3] * u0.w
                    + vf[4] * u1.x + vf[5] * u1.y + vf[6] * u1.z + vf[7] * u1.w;
        }
    }
    __shared__ float red[10][4];
    int lane = tid & 63, wv = tid >> 6;
#pragma unroll
    for (int c = 0; c < 10; ++c) {
        float s = acc[c];
#pragma unroll
        for (int o = 32; o > 0; o >>= 1) s += __shfl_down(s, o, 64);
        if (lane == 0) red[c][wv] = s;
    }
    __syncthreads();
    if (tid < 10) {
        float s = red[tid][0] + red[tid][1] + red[tid][2] + red[tid][3];
        if (ks == 0) s += fb[tid];
        atomicAdd(&out[b * 10 + tid], s);
    }
}

// ---------------- launch ----------------
extern "C" void kernel_launch(void* const* d_in, const int* in_sizes, int n_in,
                              void* d_out, int out_size, void* d_ws, size_t ws_size,
                              hipStream_t stream) {
    const float* x  = (const float*)d_in[0];
    const float* bw = (const float*)d_in[1];
    const float* w2 = (const float*)d_in[2];
    const float* fw = (const float*)d_in[3];
    const float* fb = (const float*)d_in[4];
    float* out = (float*)d_out;
    char* ws = (char*)d_ws;

    float*          w1   = (float*)(ws);
    __hip_bfloat16* Amat = (__hip_bfloat16*)(ws + 4608);
    __hip_bfloat16* hl   = (__hip_bfloat16*)(ws + 594432);
    __hip_bfloat16* p    = (__hip_bfloat16*)(ws + 118563328);

    hipMemsetAsync(d_out, 0, (size_t)out_size * sizeof(float), stream);
    k_rot  <<<1153, 256, 0, stream>>>(bw, w2, w1, Amat);
    k_conv1<<<7680, 256, 0, stream>>>(x, w1, hl);
    k_conv2<<<1568, 512, 0, stream>>>(Amat, hl, p);
    k_fc   <<<2048, 256, 0, stream>>>(p, fw, fb, out);
}

// Round 11
// 333.580 us; speedup vs baseline: 1.3463x; 1.0361x over previous
//
#include <hip/hip_runtime.h>
#include <hip/hip_bf16.h>
#include <cstdint>

#define AS1 __attribute__((address_space(1)))
#define AS3 __attribute__((address_space(3)))

typedef __bf16 bf16x8 __attribute__((ext_vector_type(8)));
typedef float  f32x16 __attribute__((ext_vector_type(16)));

__device__ __forceinline__ void gld_lds16(const void* g, void* l) {
    __builtin_amdgcn_global_load_lds((const AS1 void*)g, (AS3 void*)l, 16, 0, 0);
}

// ---------------- Kernel 0: rotated 3x3 kernels + A-matrix build ----------------
// Block 0: w1 (exact fp32 replica of the bilinear rotation), threads 0..127.
// Blocks 1..1152: build the bf16 GEMM A matrix in MFMA-FRAGMENT-LINEAR order.
__global__ __launch_bounds__(256) void k_rot(const float* __restrict__ base,
                                             const float* __restrict__ w2,
                                             float* __restrict__ w1,
                                             __hip_bfloat16* __restrict__ A) {
    int tid = threadIdx.x;
    if (blockIdx.x == 0) {
        if (tid < 128) {
            int m = tid;                // 0..127 = g*16+o
            int g = m >> 4, o = m & 15;
            float th = 6.28318530717958647692f * (float)g / 8.0f;
            float c = cosf(th), s = sinf(th);
            for (int i = 0; i < 3; ++i) {
                float ys = (2.0f * i + 1.0f) / 3.0f - 1.0f;
                for (int j = 0; j < 3; ++j) {
                    float xs = (2.0f * j + 1.0f) / 3.0f - 1.0f;
                    float gx = c * xs - s * ys;
                    float gy = s * xs + c * ys;
                    float px = ((gx + 1.0f) * 3.0f - 1.0f) * 0.5f;
                    float py = ((gy + 1.0f) * 3.0f - 1.0f) * 0.5f;
                    float x0 = floorf(px), y0 = floorf(py);
                    float wx = px - x0, wy = py - y0;
                    int x0i = (int)x0, y0i = (int)y0;
                    auto gat = [&](int yi, int xi) -> float {
                        bool v = (yi >= 0) && (yi < 3) && (xi >= 0) && (xi < 3);
                        int yc = min(max(yi, 0), 2), xc = min(max(xi, 0), 2);
                        return v ? base[o * 9 + yc * 3 + xc] : 0.0f;
                    };
                    w1[m * 9 + i * 3 + j] =
                          gat(y0i, x0i)         * (1.0f - wx) * (1.0f - wy)
                        + gat(y0i, x0i + 1)     * wx          * (1.0f - wy)
                        + gat(y0i + 1, x0i)     * (1.0f - wx) * wy
                        + gat(y0i + 1, x0i + 1) * wx          * wy;
                }
            }
        }
    } else {
        int i = (blockIdx.x - 1) * 256 + tid;
        int r = i / 1152, k = i - r * 1152;
        int g = r >> 5, o2 = r & 31;
        int kk = k >> 7, cch = k & 127;
        int ky = kk / 3, kx = kk - ky * 3;
        int c2 = cch >> 3, hh = cch & 7;
        int gi = (g - hh) & 7;
        float val = w2[((o2 * 16 + c2) * 8 + gi) * 9 + ky * 3 + kx];
        // fragment-linear placement:
        //   A_byte = (t*2+mh)*16384 + (i2*4+ks)*1024 + (hi*32+row)*16 + e*2
        int half = cch >> 6, kt = cch & 63;
        int t = kk * 2 + half, ks2 = kt >> 4, hi2 = (kt >> 3) & 1, e = kt & 7;
        int mh = r >> 7, i2 = (r >> 5) & 3, row = r & 31;
        int aidx = ((((t * 2 + mh) * 16) + i2 * 4 + ks2) << 9) + ((hi2 << 5) + row) * 8 + e;
        A[aidx] = __float2bfloat16(val);
    }
}

// ---------------- Kernel 1: conv1 + relu -> channel-last padded bf16 h ----------------
// hl layout: [b][yy 0..29][xx 0..29][c 0..127], borders = 0. Uniform blocks.
__global__ __launch_bounds__(256) void k_conv1(const float* __restrict__ x,
                                               const float* __restrict__ w1g,
                                               __hip_bfloat16* __restrict__ hl) {
    int tid = threadIdx.x;

    __shared__ float w1s[1152];
    for (int i = tid; i < 1152; i += 256) w1s[i] = w1g[i];
    __syncthreads();

    const int c0 = (tid & 15) * 8;
    float wreg[8][9];
#pragma unroll
    for (int cc = 0; cc < 8; ++cc)
#pragma unroll
        for (int k = 0; k < 9; ++k) wreg[cc][k] = w1s[(c0 + cc) * 9 + k];

    const int slot = tid >> 4;                    // 0..15
    const int band = blockIdx.x % 15;
    const int b    = blockIdx.x / 15;
    const int yy   = band * 2 + (slot >> 3);      // padded row 0..29
    const int xx0  = (slot & 7) * 4;              // 0,4,...,28

    const float* xb = x + b * 784;
    float xv[3][6];
#pragma unroll
    for (int t = 0; t < 3; ++t) {
        int sy = yy - 2 + t;
        bool syok = (sy >= 0) && (sy < 28);
#pragma unroll
        for (int u = 0; u < 6; ++u) {
            int sx = xx0 - 2 + u;
            bool ok = syok && (sx >= 0) && (sx < 28);
            xv[t][u] = ok ? xb[sy * 28 + sx] : 0.0f;
        }
    }

    float acc[4][8];
#pragma unroll
    for (int j = 0; j < 4; ++j)
#pragma unroll
        for (int cc = 0; cc < 8; ++cc) acc[j][cc] = 0.0f;

#pragma unroll
    for (int t = 0; t < 3; ++t)
#pragma unroll
        for (int u = 0; u < 3; ++u) {
#pragma unroll
            for (int j = 0; j < 4; ++j) {
                float xvv = xv[t][j + u];
#pragma unroll
                for (int cc = 0; cc < 8; ++cc)
                    acc[j][cc] += xvv * wreg[cc][t * 3 + u];
            }
        }

#pragma unroll
    for (int j = 0; j < 4; ++j) {
        int xx = xx0 + j;
        if (xx < 30) {
            bool interior = (yy >= 1) && (yy <= 28) && (xx >= 1) && (xx <= 28);
            union { __hip_bfloat16 h[8]; float4 f4; } u;
#pragma unroll
            for (int cc = 0; cc < 8; ++cc)
                u.h[cc] = __float2bfloat16(interior ? fmaxf(acc[j][cc], 0.0f) : 0.0f);
            int pi = b * 900 + yy * 30 + xx;
            *(float4*)(hl + (size_t)pi * 128 + c0) = u.f4;
        }
    }
}

// ---------------- Kernel 2: conv2 implicit GEMM — R4/R10 (verified best: 228 µs) ----
// frag-linear A (32KB linear staging, lane-linear conflict-free reads) + XOR-swizzled
// B (pre-swizzled gld_lds source); 8 waves x 128x64; one __syncthreads per K-tile;
// SGB program pinning {staging, ks0-frags, 1:1 MFMA:ds_read interleave}.
__global__ __launch_bounds__(512, 2) void k_conv2(const __hip_bfloat16* __restrict__ A,
                                                  const __hip_bfloat16* __restrict__ hl,
                                                  __hip_bfloat16* __restrict__ p) {
    __shared__ __align__(16) char smem[131072];   // 2 x (A 32KB | B 32KB)

    const int tid  = threadIdx.x;
    const int lane = tid & 63;
    const int w    = tid >> 6;          // 0..7
    const int hi   = lane >> 5;
    const int wqr  = w >> 2;            // 0..1  M-group (128 rows each)
    const int wqc  = w & 3;             // 0..3  N-group (64 cols each)

    const int bid = blockIdx.x;         // grid 1568 = 8 * 196
    const int nt  = (bid & 7) * 196 + (bid >> 3);   // bijective XCD swizzle
    const int n0  = nt << 8;            // 256 N per tile

    // ---- B staging addresses: wave w stages ch = 2w+q of each 16KB half ----
    uint32_t bSrc[2][2], ldsCh[2];
#pragma unroll
    for (int q = 0; q < 2; ++q) {
        int ch = 2 * w + q;
        int rl = ch * 8 + (lane >> 3);                 // row within 128-row half
        int ca = (lane & 7) ^ (rl & 7) ^ (ch & 3);     // pre-swizzled 16B column
        ldsCh[q] = (uint32_t)(ch * 1024);
#pragma unroll
        for (int hn = 0; hn < 2; ++hn) {
            int n = n0 + hn * 128 + rl;
            int b = n / 784; int rr = n - b * 784;
            int y = rr / 28; int xx = rr - y * 28;
            bSrc[q][hn] = (uint32_t)(((b * 30 + y) * 30 + xx) * 256 + ca * 16);
        }
    }

    // ---- B fragment read addresses (2 frags per wave), relative to B base ----
    uint32_t bRd[2]; int bSw[2];
#pragma unroll
    for (int j = 0; j < 2; ++j) {
        int r = wqc * 64 + j * 32 + (lane & 31);       // 0..255
        bRd[j] = (uint32_t)((r >> 7) * 16384 + (r & 127) * 128);
        bSw[j] = (r & 7) ^ ((r >> 3) & 3);
    }

    // ---- A read base: wave's m-half block, lane-linear ----
    const uint32_t aRd = (uint32_t)(wqr * 16384 + lane * 16);

    f32x16 acc[4][2];
#pragma unroll
    for (int i = 0; i < 4; ++i)
#pragma unroll
        for (int j = 0; j < 2; ++j) acc[i][j] = (f32x16)(0.0f);

    const char* Ab = (const char*)A;
    const char* Hb = (const char*)hl;

    auto stage = [&](int tt, char* dst) {
        // A: contiguous 32KB at tt*32768, fully linear
#pragma unroll
        for (int q = 0; q < 4; ++q)
            gld_lds16(Ab + (size_t)tt * 32768 + q * 8192 + tid * 16,
                      dst + q * 8192 + tid * 16);
        // B: pre-swizzled source, linear dest
        int kk = tt >> 1, half = tt & 1;
        int ky = kk / 3, kx = kk - ky * 3;
        uint32_t boff = (uint32_t)((ky * 30 + kx) * 256 + half * 128);
        gld_lds16(Hb + bSrc[0][0] + boff, dst + 32768 + ldsCh[0]);
        gld_lds16(Hb + bSrc[1][0] + boff, dst + 32768 + ldsCh[1]);
        gld_lds16(Hb + bSrc[0][1] + boff, dst + 49152 + ldsCh[0]);
        gld_lds16(Hb + bSrc[1][1] + boff, dst + 49152 + ldsCh[1]);
    };

    // ---- prologue: stage tile 0 into buf0 ----
    stage(0, smem);

#pragma unroll 1
    for (int t = 0; t < 17; ++t) {
        __syncthreads();             // drains staging of tile t (issued last iter)
        char* cur = smem + ((t & 1) << 16);
        const char* LA = cur + aRd;
        const char* LB = cur + 32768;
        stage(t + 1, smem + (((t + 1) & 1) << 16));   // unconditional: body branch-free

        bf16x8 aF[2][4], bF[2][2];
        // ks0 fragments
#pragma unroll
        for (int i = 0; i < 4; ++i)
            aF[0][i] = *(const bf16x8*)(LA + ((i * 4 + 0) << 10));
#pragma unroll
        for (int j = 0; j < 2; ++j)
            bF[0][j] = *(const bf16x8*)(LB + bRd[j] + ((uint32_t)((0 + hi) ^ bSw[j]) << 4));

#pragma unroll
        for (int ks = 0; ks < 4; ++ks) {
            const int c = ks & 1, nx = c ^ 1;
            if (ks < 3) {
#pragma unroll
                for (int i = 0; i < 4; ++i)
                    aF[nx][i] = *(const bf16x8*)(LA + ((i * 4 + ks + 1) << 10));
#pragma unroll
                for (int j = 0; j < 2; ++j)
                    bF[nx][j] = *(const bf16x8*)(LB + bRd[j] + ((uint32_t)(((ks + 1) * 2 + hi) ^ bSw[j]) << 4));
            }
#pragma unroll
            for (int i = 0; i < 4; ++i)
#pragma unroll
                for (int j = 0; j < 2; ++j)
                    acc[i][j] = __builtin_amdgcn_mfma_f32_32x32x16_bf16(aF[c][i], bF[c][j], acc[i][j], 0, 0, 0);
        }

        // ---- scheduling program for this region ----
        // masks: MFMA=0x8, VMEM|VMEM_READ=0x30, DS_READ=0x100
        __builtin_amdgcn_sched_group_barrier(0x030, 8, 0);   // staging first
        __builtin_amdgcn_sched_group_barrier(0x100, 6, 0);   // ks0 frags
#pragma unroll
        for (int ks = 0; ks < 3; ++ks) {
#pragma unroll
            for (int r = 0; r < 6; ++r) {
                __builtin_amdgcn_sched_group_barrier(0x008, 1, 0);
                __builtin_amdgcn_sched_group_barrier(0x100, 1, 0);
            }
            __builtin_amdgcn_sched_group_barrier(0x008, 2, 0);
        }
        __builtin_amdgcn_sched_group_barrier(0x008, 8, 0);   // ks3 MFMAs
    }

    // ---- drain: tile 17 from buf1, no staging ----
    {
        __syncthreads();
        char* cur = smem + 65536;
        const char* LA = cur + aRd;
        const char* LB = cur + 32768;

        bf16x8 aF[2][4], bF[2][2];
#pragma unroll
        for (int i = 0; i < 4; ++i)
            aF[0][i] = *(const bf16x8*)(LA + ((i * 4 + 0) << 10));
#pragma unroll
        for (int j = 0; j < 2; ++j)
            bF[0][j] = *(const bf16x8*)(LB + bRd[j] + ((uint32_t)((0 + hi) ^ bSw[j]) << 4));

#pragma unroll
        for (int ks = 0; ks < 4; ++ks) {
            const int c = ks & 1, nx = c ^ 1;
            if (ks < 3) {
#pragma unroll
                for (int i = 0; i < 4; ++i)
                    aF[nx][i] = *(const bf16x8*)(LA + ((i * 4 + ks + 1) << 10));
#pragma unroll
                for (int j = 0; j < 2; ++j)
                    bF[nx][j] = *(const bf16x8*)(LB + bRd[j] + ((uint32_t)(((ks + 1) * 2 + hi) ^ bSw[j]) << 4));
            }
#pragma unroll
            for (int i = 0; i < 4; ++i)
#pragma unroll
                for (int j = 0; j < 2; ++j)
                    acc[i][j] = __builtin_amdgcn_mfma_f32_32x32x16_bf16(aF[c][i], bF[c][j], acc[i][j], 0, 0, 0);
        }
    }

    // ---- epilogue: relu + mean over 8 consecutive M-rows; bf16 store ----
#pragma unroll
    for (int i = 0; i < 4; ++i) {
#pragma unroll
        for (int j = 0; j < 2; ++j) {
            f32x16 v = acc[i][j];
#pragma unroll
            for (int u = 0; u < 4; ++u) {
                float sv = fmaxf(v[4*u], 0.0f) + fmaxf(v[4*u+1], 0.0f)
                         + fmaxf(v[4*u+2], 0.0f) + fmaxf(v[4*u+3], 0.0f);
                sv += __shfl_xor(sv, 32, 64);
                if (hi == 0) {
                    int a = wqr * 16 + i * 4 + u;
                    int n = n0 + wqc * 64 + j * 32 + (lane & 31);
                    int b = n / 784; int rr = n - b * 784;
                    p[(b * 32 + a) * 784 + rr] = __float2bfloat16(sv * 0.125f);
                }
            }
        }
    }
}

// ---------------- Kernel 3: FC — 8 images/block to amortize fw reads ----------------
// Old fc: 2048 blocks x 1 image -> fw re-read 2048x (512 MB through L2, ~15 µs).
// New: grid 256 = 64 b-groups (8 images) x 4 k-splits. Each iteration loads the
// 10-class fw octet ONCE (320 B) and applies to 8 images -> fw L2 traffic /8 (64 MB).
// p HBM traffic unchanged (25.7 MB). acc 80 + fw 80 regs ~ 200 VGPR.
__global__ __launch_bounds__(256) void k_fc(const __hip_bfloat16* __restrict__ p,
                                            const float* __restrict__ fw,
                                            const float* __restrict__ fb,
                                            float* __restrict__ out) {
    int bg = blockIdx.x >> 2, ks = blockIdx.x & 3;   // bg: 0..63, 8 images each
    int tid = threadIdx.x;
    const float4* w4 = (const float4*)fw;
    float acc[8][10];
#pragma unroll
    for (int bb = 0; bb < 8; ++bb)
#pragma unroll
        for (int c = 0; c < 10; ++c) acc[bb][c] = 0.0f;

    for (int t = ks * 784 + tid; t < (ks + 1) * 784; t += 256) {
        float4 u0[10], u1[10];
#pragma unroll
        for (int c = 0; c < 10; ++c) {
            u0[c] = w4[c * 6272 + 2 * t];
            u1[c] = w4[c * 6272 + 2 * t + 1];
        }
#pragma unroll
        for (int bb = 0; bb < 8; ++bb) {
            union { bf16x8 v; __hip_bfloat16 h[8]; } u;
            u.v = *(const bf16x8*)(p + (size_t)(bg * 8 + bb) * 25088 + (size_t)t * 8);
            float vf[8];
#pragma unroll
            for (int e = 0; e < 8; ++e) vf[e] = __bfloat162float(u.h[e]);
#pragma unroll
            for (int c = 0; c < 10; ++c)
                acc[bb][c] += vf[0] * u0[c].x + vf[1] * u0[c].y + vf[2] * u0[c].z + vf[3] * u0[c].w
                            + vf[4] * u1[c].x + vf[5] * u1[c].y + vf[6] * u1[c].z + vf[7] * u1[c].w;
        }
    }

    __shared__ float red[8][10][4];
    int lane = tid & 63, wv = tid >> 6;
#pragma unroll
    for (int bb = 0; bb < 8; ++bb)
#pragma unroll
        for (int c = 0; c < 10; ++c) {
            float s = acc[bb][c];
#pragma unroll
            for (int o = 32; o > 0; o >>= 1) s += __shfl_down(s, o, 64);
            if (lane == 0) red[bb][c][wv] = s;
        }
    __syncthreads();
    if (tid < 80) {
        int bb = tid / 10, c = tid - bb * 10;
        float s = red[bb][c][0] + red[bb][c][1] + red[bb][c][2] + red[bb][c][3];
        if (ks == 0) s += fb[c];
        atomicAdd(&out[(bg * 8 + bb) * 10 + c], s);
    }
}

// ---------------- launch ----------------
extern "C" void kernel_launch(void* const* d_in, const int* in_sizes, int n_in,
                              void* d_out, int out_size, void* d_ws, size_t ws_size,
                              hipStream_t stream) {
    const float* x  = (const float*)d_in[0];
    const float* bw = (const float*)d_in[1];
    const float* w2 = (const float*)d_in[2];
    const float* fw = (const float*)d_in[3];
    const float* fb = (const float*)d_in[4];
    float* out = (float*)d_out;
    char* ws = (char*)d_ws;

    float*          w1   = (float*)(ws);
    __hip_bfloat16* Amat = (__hip_bfloat16*)(ws + 4608);
    __hip_bfloat16* hl   = (__hip_bfloat16*)(ws + 594432);
    __hip_bfloat16* p    = (__hip_bfloat16*)(ws + 118563328);

    hipMemsetAsync(d_out, 0, (size_t)out_size * sizeof(float), stream);
    k_rot  <<<1153, 256, 0, stream>>>(bw, w2, w1, Amat);
    k_conv1<<<7680, 256, 0, stream>>>(x, w1, hl);
    k_conv2<<<1568, 512, 0, stream>>>(Amat, hl, p);
    k_fc   <<<256,  256, 0, stream>>>(p, fw, fb, out);
}